// Round 8
// baseline (277.102 us; speedup 1.0000x reference)
//
#include <hip/hip_runtime.h>
#include <hip/hip_bf16.h>

// out[64,8192] = x[64,8192] @ dequant(w2bit)[8192,8192]^T + bias
#define B_    64
#define IN_   8192
#define OUT_  8192
#define NG_   128      // quant groups per row (IN/64)
#define PB_   2048     // packed bytes per weight row (IN/4)
#define KSPLIT 16
#define KC    512      // k per block
#define NBLK  512      // grid size (2 blocks/CU, all co-resident)

typedef float    f32x16 __attribute__((ext_vector_type(16)));
typedef short    s16x8  __attribute__((ext_vector_type(8)));
typedef _Float16 f16x4  __attribute__((ext_vector_type(4)));

// ws: xfrag 0..1MB | sq 1..3MB | part 4..20MB | wq8 20..36MB | ctl @40MB
#define OFF_SQ   (1u << 20)
#define OFF_PART (4u << 20)
#define OFF_WQ8  (20u << 20)
#define OFF_CTL  (40u << 20)

__global__ __launch_bounds__(64) void k_init(int* ctl) {
    if (threadIdx.x < 4) ctl[threadIdx.x] = 0;
}

// Device-scope grid barrier. Safe: all 512 blocks are co-resident
// (64 KB LDS => exactly 2 blocks/CU x 256 CUs). Release: __threadfence
// (waitcnt+wbL2) before arrival; acquire: ACQUIRE atomic spin (buffer_inv)
// so cross-XCD L2 lines are re-fetched after the barrier.
__device__ __forceinline__ void gbar(int* cnt, int tid) {
    __syncthreads();
    if (tid == 0) {
        __threadfence();
        atomicAdd(cnt, 1);
        while (__hip_atomic_load(cnt, __ATOMIC_ACQUIRE,
                                 __HIP_MEMORY_SCOPE_AGENT) < NBLK)
            __builtin_amdgcn_s_sleep(8);
        __threadfence();
    }
    __syncthreads();
}

// Phases: A) x->bf16 frag order, scales->bf16, zps scan (+ rare i32 compact)
//         B) MFMA main, weights direct-from-wp (prefetched during A)
//         C) reduce 16 fp16 partials + bias -> out
__global__ __launch_bounds__(256, 2) void k_fused(
    const float* __restrict__ x, const unsigned char* __restrict__ wp,
    const float* __restrict__ scales, const int* __restrict__ zps,
    const float* __restrict__ bias, float* __restrict__ out, char* __restrict__ ws)
{
    __shared__ uint4 x_lds[4096];   // 64 KB

    uint4*         xfrag = (uint4*)ws;
    uint4*         sq    = (uint4*)(ws + OFF_SQ);
    _Float16*      part  = (_Float16*)(ws + OFF_PART);
    unsigned char* wq8   = (unsigned char*)(ws + OFF_WQ8);
    int*           ctl   = (int*)(ws + OFF_CTL);

    const int tid = threadIdx.x, bid = blockIdx.x;
    const int wave = tid >> 6, lane = tid & 63;
    const int h = lane >> 5, n32 = lane & 31;
    const int kidx = bid & (KSPLIT - 1), nblk = bid >> 4;
    const int colbase = nblk * 256 + wave * 64;
    int ncol[2];
    ncol[0] = colbase + n32;
    ncol[1] = colbase + 32 + n32;

    // ---- mode detect (1 KB of wp; i32-widened bytes are all <=255) ----
    const unsigned wv = ((const unsigned*)wp)[tid];
    const bool u8m = __any((int)(wv > 255u));

    // ---- early weight prefetch: flies during ALL of Phase A ----
    uint4 w[2][4];
    if (u8m) {
#pragma unroll
        for (int cg = 0; cg < 2; ++cg) {
            const uint4* wb = (const uint4*)(wp + (unsigned)ncol[cg] * PB_ + kidx * 128 + h * 64);
#pragma unroll
            for (int c = 0; c < 4; ++c) w[cg][c] = wb[c];
        }
    }

    // ================= Phase A =================
    if (bid < 256) {
        // xfrag: x fp32 -> bf16 in 32x32-A-fragment slot order (1 uint4/thr)
        const int idx = bid * 256 + tid;            // 0..65535
        const int kx = idx >> 12, slot = idx & 4095;
        const int sg = slot >> 6, ln = slot & 63;
        const int t = sg >> 1, mt = sg & 1;
        const int hh = ln >> 5, m = ln & 31;
        const float* src = x + (mt * 32 + m) * IN_ + kx * KC + hh * 256 + t * 8;
        const float4 f0 = *(const float4*)src;
        const float4 f1 = *(const float4*)(src + 4);
        __hip_bfloat162 h0 = __float22bfloat162_rn(make_float2(f0.x, f0.y));
        __hip_bfloat162 h1 = __float22bfloat162_rn(make_float2(f0.z, f0.w));
        __hip_bfloat162 h2 = __float22bfloat162_rn(make_float2(f1.x, f1.y));
        __hip_bfloat162 h3 = __float22bfloat162_rn(make_float2(f1.z, f1.w));
        uint4 o;
        o.x = *(unsigned*)&h0; o.y = *(unsigned*)&h1;
        o.z = *(unsigned*)&h2; o.w = *(unsigned*)&h3;
        xfrag[idx] = o;
    } else {
        // sq: scales fp32 -> bf16, entry (kx,n) = 8 groups (2 entries/thr)
#pragma unroll
        for (int r = 0; r < 2; ++r) {
            const int e = (bid - 256) * 512 + r * 256 + tid;   // 0..131071
            const int n = e >> 4, kx = e & 15;
            const float* sp = scales + n * NG_ + kx * 8;
            const float4 s0 = *(const float4*)sp;
            const float4 s1 = *(const float4*)(sp + 4);
            __hip_bfloat162 h0 = __float22bfloat162_rn(make_float2(s0.x, s0.y));
            __hip_bfloat162 h1 = __float22bfloat162_rn(make_float2(s0.z, s0.w));
            __hip_bfloat162 h2 = __float22bfloat162_rn(make_float2(s1.x, s1.y));
            __hip_bfloat162 h3 = __float22bfloat162_rn(make_float2(s1.z, s1.w));
            uint4 o;
            o.x = *(unsigned*)&h0; o.y = *(unsigned*)&h1;
            o.z = *(unsigned*)&h2; o.w = *(unsigned*)&h3;
            sq[(unsigned)kx * OUT_ + n] = o;
        }
    }
    {   // zps==2 scan (8 KB/block)
        int bad = 0;
        const int4* zp4 = (const int4*)zps + bid * 512;
#pragma unroll
        for (int i = 0; i < 2; ++i) {
            const int4 z = zp4[i * 256 + tid];
            bad |= (z.x != 2) | (z.y != 2) | (z.z != 2) | (z.w != 2);
        }
        if (__any(bad) && lane == 0) atomicOr(&ctl[2], 1);
    }
    if (!u8m) {
        // rare: compact int32-widened weights to raw bytes (32 KB/block)
        const int* src = (const int*)wp + bid * 32768;
        uint4* dst = (uint4*)(wq8 + bid * 32768);
#pragma unroll
        for (int i = 0; i < 8; ++i) {
            const int j = tid + i * 256;
            const int* p = src + j * 16;
            unsigned d[4];
#pragma unroll
            for (int ww = 0; ww < 4; ++ww)
                d[ww] = (unsigned)(p[ww*4] & 0xFF) | ((unsigned)(p[ww*4+1] & 0xFF) << 8) |
                        ((unsigned)(p[ww*4+2] & 0xFF) << 16) | ((unsigned)(p[ww*4+3] & 0xFF) << 24);
            dst[j] = (uint4){d[0], d[1], d[2], d[3]};
        }
    }

    gbar(&ctl[0], tid);

    // ================= Phase B =================
    if (!u8m) {
#pragma unroll
        for (int cg = 0; cg < 2; ++cg) {
            const uint4* wb = (const uint4*)(wq8 + (unsigned)ncol[cg] * PB_ + kidx * 128 + h * 64);
#pragma unroll
            for (int c = 0; c < 4; ++c) w[cg][c] = wb[c];
        }
    }
    uint2 sv[2];
    const uint2* sq2 = (const uint2*)sq;
#pragma unroll
    for (int cg = 0; cg < 2; ++cg)
        sv[cg] = sq2[((unsigned)kidx * OUT_ + ncol[cg]) * 2 + h];
    const bool zgen =
        (__hip_atomic_load(&ctl[2], __ATOMIC_RELAXED, __HIP_MEMORY_SCOPE_AGENT) != 0);

    // x tile -> LDS (16 B/lane DMA, frag-slot order)
#pragma unroll
    for (int i = 0; i < 16; ++i) {
        const int sg = wave * 16 + i;
        const uint4* src = xfrag + kidx * 4096 + sg * 64 + lane;
        __builtin_amdgcn_global_load_lds(
            (const __attribute__((address_space(1))) unsigned*)src,
            (__attribute__((address_space(3))) unsigned*)((char*)x_lds + sg * 1024),
            16, 0, 0);
    }
    __syncthreads();   // drain DMA + sv

    // dequant LUTs: {(c-zp)*s} bf16; tl={v0,v1}, th={v2,v3}; index = chunk
    unsigned tl[2][4], th[2][4];
#pragma unroll
    for (int cg = 0; cg < 2; ++cg) {
#pragma unroll
        for (int gg = 0; gg < 4; ++gg) {
            const unsigned dwv = (gg >> 1) ? sv[cg].y : sv[cg].x;
            const unsigned s16 = (gg & 1) ? (dwv >> 16) : (dwv & 0xFFFFu);
            if (!zgen) {   // zp==2: {-2s,-s,0,s}; -2s = exp+1 with sign
                const unsigned m1 = s16 | 0x8000u;
                const unsigned m2 = (s16 + 0x0080u) | 0x8000u;
                tl[cg][gg] = m2 | (m1 << 16);
                th[cg][gg] = s16 << 16;
            } else {
                union { unsigned u; float f; } sf; sf.u = s16 << 16;
                const int g = kidx * 8 + h * 4 + gg;
                const float zf = (float)zps[ncol[cg] * NG_ + g];
                const float v0 = (0.f - zf) * sf.f, v1 = (1.f - zf) * sf.f;
                const float v2 = (2.f - zf) * sf.f, v3 = (3.f - zf) * sf.f;
                __hip_bfloat162 lo = __float22bfloat162_rn(make_float2(v0, v1));
                __hip_bfloat162 hi = __float22bfloat162_rn(make_float2(v2, v3));
                tl[cg][gg] = *(unsigned*)&lo;
                th[cg][gg] = *(unsigned*)&hi;
            }
        }
    }

    f32x16 acc[2][2];
#pragma unroll
    for (int cg = 0; cg < 2; ++cg)
#pragma unroll
        for (int mt = 0; mt < 2; ++mt)
#pragma unroll
            for (int r = 0; r < 16; ++r) acc[cg][mt][r] = 0.f;

    // pure-register/LDS K-loop: 4 chunks x 8 steps x (2cg x 2mt MFMA)
#pragma unroll
    for (int c = 0; c < 4; ++c) {
#pragma unroll
        for (int dw = 0; dw < 4; ++dw) {
#pragma unroll
            for (int hf = 0; hf < 2; ++hf) {
                const int t = c * 8 + dw * 2 + hf;
                union { uint4 u4; s16x8 s8; } av[2];
#pragma unroll
                for (int mt = 0; mt < 2; ++mt)
                    av[mt].u4 = x_lds[(t * 2 + mt) * 64 + lane];
#pragma unroll
                for (int cg = 0; cg < 2; ++cg) {
                    const unsigned wdw = ((const unsigned*)&w[cg][c])[dw];
                    const unsigned u = hf ? (wdw >> 16) : (wdw & 0xFFFFu);
                    const unsigned tlv = tl[cg][c], thv = th[cg][c];
                    union { unsigned w_[4]; s16x8 s8; } bf;
#pragma unroll
                    for (int m = 0; m < 4; ++m) {
                        const unsigned c0 = (u >> (4 * m)) & 3u;
                        const unsigned c1 = (u >> (4 * m + 2)) & 3u;
                        const unsigned sel = 0x01000100u + c0 * 0x0202u + c1 * 0x02020000u;
                        bf.w_[m] = __builtin_amdgcn_perm(thv, tlv, sel);
                    }
#pragma unroll
                    for (int mt = 0; mt < 2; ++mt)
                        acc[cg][mt] = __builtin_amdgcn_mfma_f32_32x32x16_bf16(
                            av[mt].s8, bf.s8, acc[cg][mt], 0, 0, 0);
                }
            }
        }
    }

    // epilogue: fp16 partial plane; C/D: col=lane&31, row=(r&3)+8*(r>>2)+4*h
    _Float16* pp = part + kidx * (B_ * OUT_);
#pragma unroll
    for (int cg = 0; cg < 2; ++cg) {
#pragma unroll
        for (int mt = 0; mt < 2; ++mt)
#pragma unroll
            for (int r = 0; r < 16; ++r) {
                const int row = (r & 3) + 8 * (r >> 2) + 4 * h;
                pp[(mt * 32 + row) * OUT_ + ncol[cg]] = (_Float16)acc[cg][mt][r];
            }
    }

    gbar(&ctl[1], tid);

    // ================= Phase C =================
    const int i4 = (bid * 256 + tid) * 4;          // 0..524287 (=B_*OUT_)
    const int b = i4 >> 13, n0 = i4 & (OUT_ - 1);
    float4 s = *(const float4*)(bias + n0);
#pragma unroll
    for (int p = 0; p < KSPLIT; ++p) {
        const f16x4 v = *(const f16x4*)(part + p * (B_ * OUT_) + b * OUT_ + n0);
        s.x += (float)v[0]; s.y += (float)v[1];
        s.z += (float)v[2]; s.w += (float)v[3];
    }
    *(float4*)(out + i4) = s;
}

extern "C" void kernel_launch(void* const* d_in, const int* in_sizes, int n_in,
                              void* d_out, int out_size, void* d_ws, size_t ws_size,
                              hipStream_t stream) {
    const float*         x      = (const float*)d_in[0];
    const unsigned char* wp     = (const unsigned char*)d_in[1];
    const float*         scales = (const float*)d_in[2];
    const int*           zps    = (const int*)d_in[3];
    const float*         bias   = (const float*)d_in[4];
    float*               out    = (float*)d_out;
    int*                 ctl    = (int*)((char*)d_ws + OFF_CTL);

    k_init<<<1, 64, 0, stream>>>(ctl);
    k_fused<<<NBLK, 256, 0, stream>>>(x, wp, scales, zps, bias, out, (char*)d_ws);
}